// Round 2
// baseline (20066.908 us; speedup 1.0000x reference)
//
#include <hip/hip_runtime.h>
#include <math.h>

#define NB   32
#define NT   2000
#define NFIN 256
#define NH   1024
#define NOUT 256
#define KC   1280            // 1024 (r) + 256 (x)
#define GRID 256
#define BLK  256
#define HALF 128             // blocks per independent barrier group (one batch-half)

typedef float f32x4 __attribute__((ext_vector_type(4)));

// ---- LDS partition (in floats) ----
#define WC_STR 12            // 8 cols + 4 pad
#define OFF_WC   0                          // 1280*12 = 15360
#define OFF_WOT  (OFF_WC + KC * WC_STR)     // 2*1024  =  2048  (interleaved [k][2])
#define XS_STR   20                         // 16 batches + 4 pad
#define OFF_XS   (OFF_WOT + 2 * NH)         // 256*20  =  5120
#define PD_STR   68                         // 64 ks5 + 4 pad (transposed: [out][ks5])
#define OFF_PD   (OFF_XS + NFIN * XS_STR)   // 160*68  = 10880
#define LDS_FLOATS (OFF_PD + 160 * PD_STR)  // 33408 floats
#define LDS_BYTES  (LDS_FLOATS * 4)         // 133632 B (< 160 KiB)

// ---------------------------------------------------------------------------
// Wcomb block layout: Wcb[cg][k][8] = column 8*cg+jj at row k.
//   k <  1024 : 1.2*Wr[k][j] + sum_o Wo[k][o]*Wf[o][j]   (Weff = G*Wr + Wo@Wf)
//   k >= 1024 : Wi[k-1024][j]
// Also emits Wo^T: Wot[o][k] = Wo[k][o].
// ---------------------------------------------------------------------------
__global__ __launch_bounds__(256) void init_wcomb(
    const float* __restrict__ Wr, const float* __restrict__ Wi,
    const float* __restrict__ Wf, const float* __restrict__ Wo,
    float* __restrict__ Wcb, float* __restrict__ Wot)
{
    __shared__ float wo_s[NOUT];
    const int k   = blockIdx.x;      // 0..1279
    const int tid = threadIdx.x;
    float acc[4];
    if (k < NH) {
        wo_s[tid] = Wo[k * NOUT + tid];
        __syncthreads();
        Wot[(size_t)tid * NH + k] = wo_s[tid];   // transpose Wo
#pragma unroll
        for (int jj = 0; jj < 4; ++jj)
            acc[jj] = 1.2f * Wr[k * NH + jj * 256 + tid];
        for (int o = 0; o < NOUT; ++o) {
            const float w = wo_s[o];
#pragma unroll
            for (int jj = 0; jj < 4; ++jj)
                acc[jj] = fmaf(w, Wf[o * NH + jj * 256 + tid], acc[jj]);
        }
    } else {
        const int k2 = k - NH;
#pragma unroll
        for (int jj = 0; jj < 4; ++jj)
            acc[jj] = Wi[k2 * NH + jj * 256 + tid];
    }
#pragma unroll
    for (int jj = 0; jj < 4; ++jj) {
        const int j = jj * 256 + tid;
        Wcb[(size_t)(j >> 3) * (KC * 8) + k * 8 + (j & 7)] = acc[jj];
    }
}

// ---------------------------------------------------------------------------
// Per-batch init (k-major): c_km[j][b] = (xi_o @ Wf)[b][j],
// xih_km[j][b] = xi_h[b][j], r0[j][b] = xi_h (u0=0 -> tanh(0)=0).
// Also zeroes the barrier array (256 unsigneds).
// ---------------------------------------------------------------------------
__global__ __launch_bounds__(256) void init_state(
    const float* __restrict__ Wf, const float* __restrict__ xi_o,
    const float* __restrict__ xi_h,
    float* __restrict__ c_km, float* __restrict__ xih_km,
    float* __restrict__ r0, unsigned* __restrict__ bar)
{
    __shared__ float xo_s[NOUT];
    const int b   = blockIdx.x;
    const int tid = threadIdx.x;
    if (b == 0) bar[tid] = 0u;           // zero counters + flags (256 uints)
    xo_s[tid] = xi_o[b * NOUT + tid];
    __syncthreads();
    float acc[4] = {0.f, 0.f, 0.f, 0.f};
    for (int o = 0; o < NOUT; ++o) {
        const float x = xo_s[o];
#pragma unroll
        for (int jj = 0; jj < 4; ++jj)
            acc[jj] = fmaf(x, Wf[o * NH + jj * 256 + tid], acc[jj]);
    }
#pragma unroll
    for (int jj = 0; jj < 4; ++jj) {
        const int j = jj * 256 + tid;
        const float xh = xi_h[b * NH + j];
        c_km[j * NB + b]   = acc[jj];
        xih_km[j * NB + b] = xh;
        r0[j * NB + b]     = xh;
    }
}

// ---------------------------------------------------------------------------
// Persistent kernel: 256 blocks x 256 threads. Block (bg=blk&1, cg=blk>>1):
// 16 batches x 8 du-cols + 2 z-cols. Thread (ks5=tid>>2, bq=tid&3): 64-way
// cyclic K split, tile 4 batches x (8 du + 2 z) accumulators.
//
// Coherence scheme (no agent fences): r double-buffers are accessed ONLY via
// sc0-sc1 (coherence-point) loads/stores -> L2 never holds r -> no buffer_inv
// needed -> x / weights / constants stay L2-resident across steps. Ordering:
// per-wave s_waitcnt vmcnt(0) after the r store, __syncthreads, then the
// relaxed fetch_add (same-wave in-order issue => r at L3 before arrive).
// ---------------------------------------------------------------------------
extern "C" __global__ __launch_bounds__(BLK, 1) void reservoir_persistent(
    const float* __restrict__ x_all,  // [32][2000][256]
    const float* __restrict__ Wcb,    // [128][1280][8]
    const float* __restrict__ Wot,    // [256][1024]
    const float* __restrict__ c_km,   // [1024][32]
    const float* __restrict__ xih_km, // [1024][32]
    const float* __restrict__ xi_o,   // [32][256]
    float* __restrict__ r0, float* __restrict__ r1,   // [1024][32] each
    float* __restrict__ out,          // [32][2000][256]
    unsigned* __restrict__ bar)
{
    extern __shared__ float sm[];
    float* Wc_s  = sm + OFF_WC;
    float* Wot_s = sm + OFF_WOT;     // interleaved: Wot_s[k*2 + col]
    float* x_s   = sm + OFF_XS;
    float* pd    = sm + OFF_PD;      // [160][PD_STR]: rows 0..127 du, 128..159 z

    const int tid = threadIdx.x;
    const int blk = blockIdx.x;
    const int bg  = blk & 1;
    const int cg  = blk >> 1;
    const int b0  = bg * 16;
    const int j0  = cg * 8;
    const int zc0 = cg * 2;

    // barrier slots, 256B apart: cnt at bar[bg*64], flag at bar[128+bg*64]
    unsigned* cnt = bar + (bg << 6);
    unsigned* flg = bar + 128 + (bg << 6);

    // ---- one-time: W tiles into LDS ----
#pragma unroll
    for (int i = 0; i < 10; ++i) {
        const int q = tid + BLK * i;          // 2560 float4 quads
        const int k = q >> 1, h = q & 1;
        const float4 w = *(const float4*)&Wcb[(size_t)cg * (KC * 8) + k * 8 + h * 4];
        *(float4*)&Wc_s[k * WC_STR + h * 4] = w;
    }
#pragma unroll
    for (int i = 0; i < 8; ++i) {
        const int idx = tid + BLK * i;        // idx = col*1024 + k
        Wot_s[((idx & 1023) << 1) | (idx >> 10)] = Wot[(size_t)zc0 * NH + idx];
    }

    // ---- epilogue state in registers ----
    float u_reg = 0.f, c_reg = 0.f, xih_reg = 0.f;
    int ep_addr = 0;
    if (tid < 128) {
        const int j = j0 + (tid >> 4);
        const int b = b0 + (tid & 15);
        ep_addr = j * NB + b;
        c_reg   = c_km[ep_addr];
        xih_reg = xih_km[ep_addr];
    }
    float zxi = 0.f; size_t z_out_base = 0;
    if (tid >= 128 && tid < 160) {
        const int o2 = tid - 128;
        const int zc = zc0 + (o2 >> 4);
        const int zb = b0 + (o2 & 15);
        zxi = xi_o[zb * NOUT + zc];
        z_out_base = (size_t)zb * NT * NOUT + zc;
    }

    const int ks5 = tid >> 2;   // 0..63
    const int bq  = tid & 3;    // 0..3
    // x-stage mapping (swizzled for conflict-free LDS stores)
    const int bb  = tid & 15;   // batch row
    const int q2  = tid >> 4;   // quad group 0..15

    const float* rcur = r0;
    float*       rnxt = r1;

    // ---- stage x for t=0 ----
    {
        const float* xp = x_all + ((size_t)(b0 + bb) * NT + 0) * NFIN;
#pragma unroll
        for (int i = 0; i < 4; ++i) {
            const int kk = (q2 + 16 * i) * 4;
            const float4 v = *(const float4*)&xp[kk];
            x_s[(kk + 0) * XS_STR + bb] = v.x;
            x_s[(kk + 1) * XS_STR + bb] = v.y;
            x_s[(kk + 2) * XS_STR + bb] = v.z;
            x_s[(kk + 3) * XS_STR + bb] = v.w;
        }
    }
    __syncthreads();

    // x-part operand prefetch (A-vectors + W-vectors) for the CURRENT step.
    float4 xa[4], wx0[4], wx1[4];
    auto prefetch_xpart = [&]() {
#pragma unroll
        for (int m = 0; m < 4; ++m) {
            const int kk = ks5 + (m << 6);
            xa[m]  = *(const float4*)&x_s[kk * XS_STR + bq * 4];
            wx0[m] = *(const float4*)&Wc_s[(kk + NH) * WC_STR];
            wx1[m] = *(const float4*)&Wc_s[(kk + NH) * WC_STR + 4];
        }
    };
    prefetch_xpart();   // for t = 0

    for (int t = 0; t < NT; ++t) {
        // ---- issue ALL 16 r-loads first (sc0 sc1: read at L3, bypass L1/L2) ----
        const float* rbase = rcur + b0 + bq * 4;
        f32x4 rq4[16];
#pragma unroll
        for (int p = 0; p < 16; ++p) {
            const float* ap = rbase + (size_t)(ks5 + (p << 6)) * NB;
            asm volatile("global_load_dwordx4 %0, %1, off sc0 sc1"
                         : "=v"(rq4[p]) : "v"(ap));
        }

        float ad[8][4], az[2][4];
#pragma unroll
        for (int jj = 0; jj < 8; ++jj)
#pragma unroll
            for (int i = 0; i < 4; ++i) ad[jj][i] = 0.f;
#pragma unroll
        for (int jq = 0; jq < 2; ++jq)
#pragma unroll
            for (int i = 0; i < 4; ++i) az[jq][i] = 0.f;

        // ---- r-part m-loop in 4 chunks with staged vmcnt waits ----
#define RCHUNK(M0, M1, VW)                                                     \
        asm volatile("s_waitcnt vmcnt(" #VW ")" ::: "memory");                 \
        __builtin_amdgcn_sched_barrier(0);                                     \
        _Pragma("unroll")                                                      \
        for (int m = M0; m < M1; ++m) {                                        \
            const int k = ks5 + (m << 6);                                      \
            const f32x4 a = rq4[m];                                            \
            const float4 w0 = *(const float4*)&Wc_s[k * WC_STR];               \
            const float4 w1 = *(const float4*)&Wc_s[k * WC_STR + 4];           \
            const float2 zz = *(const float2*)&Wot_s[k * 2];                   \
            const float av[4] = {a[0], a[1], a[2], a[3]};                      \
            const float wv[8] = {w0.x, w0.y, w0.z, w0.w,                       \
                                 w1.x, w1.y, w1.z, w1.w};                      \
            _Pragma("unroll")                                                  \
            for (int i = 0; i < 4; ++i) {                                      \
                _Pragma("unroll")                                              \
                for (int jj = 0; jj < 8; ++jj)                                 \
                    ad[jj][i] = fmaf(av[i], wv[jj], ad[jj][i]);                \
                az[0][i] = fmaf(av[i], zz.x, az[0][i]);                        \
                az[1][i] = fmaf(av[i], zz.y, az[1][i]);                        \
            }                                                                  \
        }
        RCHUNK(0, 4, 12)
        RCHUNK(4, 8, 8)
        RCHUNK(8, 12, 4)
        RCHUNK(12, 16, 0)
#undef RCHUNK

        // ---- x part (k >= 1024) from prefetched regs; FMA order identical ----
#pragma unroll
        for (int m = 0; m < 4; ++m) {
            const float av[4] = {xa[m].x, xa[m].y, xa[m].z, xa[m].w};
            const float wv[8] = {wx0[m].x, wx0[m].y, wx0[m].z, wx0[m].w,
                                 wx1[m].x, wx1[m].y, wx1[m].z, wx1[m].w};
#pragma unroll
            for (int i = 0; i < 4; ++i)
#pragma unroll
                for (int jj = 0; jj < 8; ++jj)
                    ad[jj][i] = fmaf(av[i], wv[jj], ad[jj][i]);
        }

        // ---- issue t+1 x loads into registers NOW (fly under pd+sync+reduce) ----
        const int tn = (t + 1 < NT) ? (t + 1) : (NT - 1);
        float4 xv[4];
        {
            const float* xp = x_all + ((size_t)(b0 + bb) * NT + tn) * NFIN;
#pragma unroll
            for (int i = 0; i < 4; ++i)
                xv[i] = *(const float4*)&xp[(q2 + 16 * i) * 4];
        }

        // ---- partials to LDS, transposed: pd[out][ks5] ----
#pragma unroll
        for (int jj = 0; jj < 8; ++jj)
#pragma unroll
            for (int i = 0; i < 4; ++i)
                pd[(jj * 16 + bq * 4 + i) * PD_STR + ks5] = ad[jj][i];
#pragma unroll
        for (int jq = 0; jq < 2; ++jq)
#pragma unroll
            for (int i = 0; i < 4; ++i)
                pd[(128 + jq * 16 + bq * 4 + i) * PD_STR + ks5] = az[jq][i];
        __syncthreads();

        // ---- reduce (float4 over ks5) + epilogue ----
        if (tid < 160) {
            const float* row = &pd[tid * PD_STR];
            float4 s4 = make_float4(0.f, 0.f, 0.f, 0.f);
#pragma unroll
            for (int q = 0; q < 16; ++q) {
                const float4 v = *(const float4*)&row[q * 4];
                s4.x += v.x; s4.y += v.y; s4.z += v.z; s4.w += v.w;
            }
            const float s = (s4.x + s4.y) + (s4.z + s4.w);
            if (tid < 128) {
                const float un = 0.9f * u_reg + 0.1f * (s + c_reg);
                u_reg = un;
                const float rv = tanhf(un) + xih_reg;
                const float* sp = rnxt + ep_addr;
                asm volatile("global_store_dword %0, %1, off sc0 sc1"
                             :: "v"(sp), "v"(rv) : "memory");
            } else {
                out[z_out_base + (size_t)t * NOUT] = s + zxi;
            }
        }

        // drain r store (to L3) + xv loads, per wave, before the barrier
        asm volatile("s_waitcnt vmcnt(0)" ::: "memory");

        // ---- write staged x (registers -> LDS) ----
        {
#pragma unroll
            for (int i = 0; i < 4; ++i) {
                const int kk = (q2 + 16 * i) * 4;
                const float4 v = xv[i];
                x_s[(kk + 0) * XS_STR + bb] = v.x;
                x_s[(kk + 1) * XS_STR + bb] = v.y;
                x_s[(kk + 2) * XS_STR + bb] = v.z;
                x_s[(kk + 3) * XS_STR + bb] = v.w;
            }
        }
        __syncthreads();   // epilogue r-stores drained + x_s(t+1) ready, block-wide

        // ---- arrive ----
        if (tid == 0)
            __hip_atomic_fetch_add(cnt, 1u, __ATOMIC_RELAXED,
                                   __HIP_MEMORY_SCOPE_AGENT);

        // ---- overlap the wait window: prefetch x-part operands for t+1 ----
        prefetch_xpart();

        // ---- poll ----
        if (tid == 0) {
            const unsigned tgt = (unsigned)HALF * (unsigned)(t + 1);
            while (__hip_atomic_load(flg, __ATOMIC_RELAXED,
                                     __HIP_MEMORY_SCOPE_AGENT) < tgt) {
                // re-check arrivals: last arriver publishes the flag
                if (__hip_atomic_load(cnt, __ATOMIC_RELAXED,
                                      __HIP_MEMORY_SCOPE_AGENT) >= tgt) {
                    __hip_atomic_store(flg, tgt, __ATOMIC_RELAXED,
                                       __HIP_MEMORY_SCOPE_AGENT);
                    break;
                }
                __builtin_amdgcn_s_sleep(2);
            }
        }
        __syncthreads();

        float* tmp = (float*)rcur; rcur = rnxt; rnxt = tmp;
    }
}

// ---------------------------------------------------------------------------
extern "C" void kernel_launch(void* const* d_in, const int* in_sizes, int n_in,
                              void* d_out, int out_size, void* d_ws, size_t ws_size,
                              hipStream_t stream)
{
    const float* inputs = (const float*)d_in[0];  // [32,2000,256]
    const float* Wr     = (const float*)d_in[1];  // [1024,1024]
    const float* Wi     = (const float*)d_in[2];  // [256,1024]
    const float* Wf     = (const float*)d_in[3];  // [256,1024]
    const float* Wo     = (const float*)d_in[4];  // [1024,256]
    const float* xi_h   = (const float*)d_in[5];  // [32,1024]
    const float* xi_o   = (const float*)d_in[6];  // [32,256]
    float* out = (float*)d_out;

    float* ws     = (float*)d_ws;
    float* Wcb    = ws;                         // 128*1280*8
    float* Wot    = Wcb + 128 * KC * 8;         // 256*1024
    float* c_km   = Wot + NOUT * NH;
    float* xih_km = c_km + NH * NB;
    float* r0     = xih_km + NH * NB;
    float* r1     = r0 + NH * NB;
    unsigned* bar = (unsigned*)(r1 + NH * NB);  // 256 uints (cnt/flag per half)

    (void)hipFuncSetAttribute((const void*)reservoir_persistent,
                              hipFuncAttributeMaxDynamicSharedMemorySize, LDS_BYTES);

    init_wcomb<<<KC, 256, 0, stream>>>(Wr, Wi, Wf, Wo, Wcb, Wot);
    init_state<<<NB, 256, 0, stream>>>(Wf, xi_o, xi_h, c_km, xih_km, r0, bar);

    void* args[] = {
        (void*)&inputs, (void*)&Wcb, (void*)&Wot, (void*)&c_km, (void*)&xih_km,
        (void*)&xi_o, (void*)&r0, (void*)&r1, (void*)&out, (void*)&bar
    };
    (void)hipLaunchCooperativeKernel((void*)reservoir_persistent,
                                     dim3(GRID), dim3(BLK), args, LDS_BYTES, stream);
}

// Round 3
// 17836.221 us; speedup vs baseline: 1.1251x; 1.1251x over previous
//
#include <hip/hip_runtime.h>
#include <math.h>

#define NB   32
#define NT   2000
#define NFIN 256
#define NH   1024
#define NOUT 256
#define KC   1280            // 1024 (r) + 256 (x)
#define GRID 256
#define BLK  256
#define HALF 128             // blocks per independent barrier group (one batch-half)

// ---- LDS partition (in floats) ----
#define WC_STR 12            // 8 cols + 4 pad
#define OFF_WC   0                          // 1280*12 = 15360
#define OFF_WOT  (OFF_WC + KC * WC_STR)     // 2*1024  =  2048
#define XS_STR   20                         // 16 batches + 4 pad
#define OFF_XS   (OFF_WOT + 2 * NH)         // 256*20  =  5120
#define PD_STR   68                         // 64 ks5 + 4 pad (transposed: [out][ks5])
#define OFF_PD   (OFF_XS + NFIN * XS_STR)   // 160*68  = 10880
#define LDS_FLOATS (OFF_PD + 160 * PD_STR)  // 33408 floats
#define LDS_BYTES  (LDS_FLOATS * 4)         // 133632 B (< 160 KiB)

// ---------------------------------------------------------------------------
// Wcomb block layout: Wcb[cg][k][8] = column 8*cg+jj at row k.
//   k <  1024 : 1.2*Wr[k][j] + sum_o Wo[k][o]*Wf[o][j]   (Weff = G*Wr + Wo@Wf)
//   k >= 1024 : Wi[k-1024][j]
// Also emits Wo^T: Wot[o][k] = Wo[k][o].
// ---------------------------------------------------------------------------
__global__ __launch_bounds__(256) void init_wcomb(
    const float* __restrict__ Wr, const float* __restrict__ Wi,
    const float* __restrict__ Wf, const float* __restrict__ Wo,
    float* __restrict__ Wcb, float* __restrict__ Wot)
{
    __shared__ float wo_s[NOUT];
    const int k   = blockIdx.x;      // 0..1279
    const int tid = threadIdx.x;
    float acc[4];
    if (k < NH) {
        wo_s[tid] = Wo[k * NOUT + tid];
        __syncthreads();
        Wot[(size_t)tid * NH + k] = wo_s[tid];   // transpose Wo
#pragma unroll
        for (int jj = 0; jj < 4; ++jj)
            acc[jj] = 1.2f * Wr[k * NH + jj * 256 + tid];
        for (int o = 0; o < NOUT; ++o) {
            const float w = wo_s[o];
#pragma unroll
            for (int jj = 0; jj < 4; ++jj)
                acc[jj] = fmaf(w, Wf[o * NH + jj * 256 + tid], acc[jj]);
        }
    } else {
        const int k2 = k - NH;
#pragma unroll
        for (int jj = 0; jj < 4; ++jj)
            acc[jj] = Wi[k2 * NH + jj * 256 + tid];
    }
#pragma unroll
    for (int jj = 0; jj < 4; ++jj) {
        const int j = jj * 256 + tid;
        Wcb[(size_t)(j >> 3) * (KC * 8) + k * 8 + (j & 7)] = acc[jj];
    }
}

// ---------------------------------------------------------------------------
// Per-batch init (k-major): c_km[j][b] = (xi_o @ Wf)[b][j],
// xih_km[j][b] = xi_h[b][j], r0[j][b] = xi_h (u0=0 -> tanh(0)=0).
// Also zeroes the barrier array (1024 unsigneds: tree cells, 64B-spaced).
// ---------------------------------------------------------------------------
__global__ __launch_bounds__(256) void init_state(
    const float* __restrict__ Wf, const float* __restrict__ xi_o,
    const float* __restrict__ xi_h,
    float* __restrict__ c_km, float* __restrict__ xih_km,
    float* __restrict__ r0, unsigned* __restrict__ bar)
{
    __shared__ float xo_s[NOUT];
    const int b   = blockIdx.x;
    const int tid = threadIdx.x;
    if (tid < 32) bar[b * 32 + tid] = 0u;   // 32 blocks x 32 = 1024 cells
    xo_s[tid] = xi_o[b * NOUT + tid];
    __syncthreads();
    float acc[4] = {0.f, 0.f, 0.f, 0.f};
    for (int o = 0; o < NOUT; ++o) {
        const float x = xo_s[o];
#pragma unroll
        for (int jj = 0; jj < 4; ++jj)
            acc[jj] = fmaf(x, Wf[o * NH + jj * 256 + tid], acc[jj]);
    }
#pragma unroll
    for (int jj = 0; jj < 4; ++jj) {
        const int j = jj * 256 + tid;
        const float xh = xi_h[b * NH + j];
        c_km[j * NB + b]   = acc[jj];
        xih_km[j * NB + b] = xh;
        r0[j * NB + b]     = xh;
    }
}

// ---------------------------------------------------------------------------
// Persistent kernel: 256 blocks x 256 threads. Block (bg=blk&1, cg=blk>>1):
// 16 batches x 8 du-cols + 2 z-cols. Thread (ks5=tid>>2, bq=tid&3): 64-way
// cyclic K split, tile 4 batches x (8 du + 2 z) accumulators.
//
// Sync scheme: producers write rnxt (and out) via sc0-sc1 write-through
// stores (straight to the coherence point; 512 B/block) -> NO release
// wbl2 fence needed. Consumers keep cached r loads (16 blocks/XCD share
// one L3->L2 refill) behind a per-step acquire buffer_inv.
// Arrival tree per half: 16 leaf counters (8 blocks each) -> root (16) ->
// flag; cuts same-line atomic serialization 128 -> ~24.
// Barrier cells 64 B apart: leaf l @ bar[bg*512 + l*16], root @ +256,
// flag @ +272.
// ---------------------------------------------------------------------------
extern "C" __global__ __launch_bounds__(BLK, 1) void reservoir_persistent(
    const float* __restrict__ x_all,  // [32][2000][256]
    const float* __restrict__ Wcb,    // [128][1280][8]
    const float* __restrict__ Wot,    // [256][1024]
    const float* __restrict__ c_km,   // [1024][32]
    const float* __restrict__ xih_km, // [1024][32]
    const float* __restrict__ xi_o,   // [32][256]
    float* __restrict__ r0, float* __restrict__ r1,   // [1024][32] each
    float* __restrict__ out,          // [32][2000][256]
    unsigned* __restrict__ bar)
{
    extern __shared__ float sm[];
    float* Wc_s  = sm + OFF_WC;
    float* Wot_s = sm + OFF_WOT;
    float* x_s   = sm + OFF_XS;
    float* pd    = sm + OFF_PD;      // [160][PD_STR]: rows 0..127 du, 128..159 z

    const int tid = threadIdx.x;
    const int blk = blockIdx.x;
    const int bg  = blk & 1;
    const int cg  = blk >> 1;
    const int b0  = bg * 16;
    const int j0  = cg * 8;
    const int zc0 = cg * 2;
    const int lf  = cg >> 3;         // leaf index 0..15 (8 blocks per leaf)

    unsigned* leaf = bar + (bg << 9) + (lf << 4);
    unsigned* root = bar + (bg << 9) + 256;
    unsigned* flg  = bar + (bg << 9) + 272;

    // ---- one-time: W tiles into LDS ----
#pragma unroll
    for (int i = 0; i < 10; ++i) {
        const int q = tid + BLK * i;          // 2560 float4 quads
        const int k = q >> 1, h = q & 1;
        const float4 w = *(const float4*)&Wcb[(size_t)cg * (KC * 8) + k * 8 + h * 4];
        *(float4*)&Wc_s[k * WC_STR + h * 4] = w;
    }
#pragma unroll
    for (int i = 0; i < 8; ++i) {
        const int idx = tid + BLK * i;        // 2048 floats
        Wot_s[idx] = Wot[(size_t)zc0 * NH + idx];
    }

    // ---- epilogue state in registers ----
    float u_reg = 0.f, c_reg = 0.f, xih_reg = 0.f;
    int ep_addr = 0;
    if (tid < 128) {
        const int j = j0 + (tid >> 4);
        const int b = b0 + (tid & 15);
        ep_addr = j * NB + b;
        c_reg   = c_km[ep_addr];
        xih_reg = xih_km[ep_addr];
    }
    float zxi = 0.f; size_t z_out_base = 0;
    if (tid >= 128 && tid < 160) {
        const int o2 = tid - 128;
        const int zc = zc0 + (o2 >> 4);
        const int zb = b0 + (o2 & 15);
        zxi = xi_o[zb * NOUT + zc];
        z_out_base = (size_t)zb * NT * NOUT + zc;
    }

    const int ks5 = tid >> 2;   // 0..63
    const int bq  = tid & 3;    // 0..3
    // x-stage mapping (swizzled for conflict-free LDS stores)
    const int bb  = tid & 15;   // batch row
    const int q2  = tid >> 4;   // quad group 0..15

    const float* rcur = r0;
    float*       rnxt = r1;

    // ---- stage x for t=0 ----
    {
        const float* xp = x_all + ((size_t)(b0 + bb) * NT + 0) * NFIN;
#pragma unroll
        for (int i = 0; i < 4; ++i) {
            const int kk = (q2 + 16 * i) * 4;
            const float4 v = *(const float4*)&xp[kk];
            x_s[(kk + 0) * XS_STR + bb] = v.x;
            x_s[(kk + 1) * XS_STR + bb] = v.y;
            x_s[(kk + 2) * XS_STR + bb] = v.z;
            x_s[(kk + 3) * XS_STR + bb] = v.w;
        }
    }
    __syncthreads();

    for (int t = 0; t < NT; ++t) {
        // ---- main GEMM walk (r part, FULL-depth prefetch: all 16 float4) ----
        float ad[8][4], az[2][4];
#pragma unroll
        for (int jj = 0; jj < 8; ++jj)
#pragma unroll
            for (int i = 0; i < 4; ++i) ad[jj][i] = 0.f;
#pragma unroll
        for (int jq = 0; jq < 2; ++jq)
#pragma unroll
            for (int i = 0; i < 4; ++i) az[jq][i] = 0.f;

        const float* rbase = rcur + b0 + bq * 4;
        float4 rq4[16];
#pragma unroll
        for (int p = 0; p < 16; ++p)
            rq4[p] = *(const float4*)(rbase + (size_t)(ks5 + (p << 6)) * NB);

#pragma unroll
        for (int m = 0; m < 16; ++m) {
            const int k = ks5 + (m << 6);
            const float4 a = rq4[m];
            const float4 w0 = *(const float4*)&Wc_s[k * WC_STR];
            const float4 w1 = *(const float4*)&Wc_s[k * WC_STR + 4];
            const float z0 = Wot_s[k], z1 = Wot_s[NH + k];
            const float av[4] = {a.x, a.y, a.z, a.w};
            const float wv[8] = {w0.x, w0.y, w0.z, w0.w, w1.x, w1.y, w1.z, w1.w};
#pragma unroll
            for (int i = 0; i < 4; ++i) {
#pragma unroll
                for (int jj = 0; jj < 8; ++jj)
                    ad[jj][i] = fmaf(av[i], wv[jj], ad[jj][i]);
                az[0][i] = fmaf(av[i], z0, az[0][i]);
                az[1][i] = fmaf(av[i], z1, az[1][i]);
            }
        }
#pragma unroll
        for (int m = 0; m < 4; ++m) {         // x part: k >= 1024
            const int kk = ks5 + (m << 6);
            const int k  = kk + NH;
            const float4 a  = *(const float4*)&x_s[kk * XS_STR + bq * 4];
            const float4 w0 = *(const float4*)&Wc_s[k * WC_STR];
            const float4 w1 = *(const float4*)&Wc_s[k * WC_STR + 4];
            const float av[4] = {a.x, a.y, a.z, a.w};
            const float wv[8] = {w0.x, w0.y, w0.z, w0.w, w1.x, w1.y, w1.z, w1.w};
#pragma unroll
            for (int i = 0; i < 4; ++i)
#pragma unroll
                for (int jj = 0; jj < 8; ++jj)
                    ad[jj][i] = fmaf(av[i], wv[jj], ad[jj][i]);
        }

        // ---- issue t+1 x loads into registers NOW (fly under pd+sync+reduce) ----
        const int tn = (t + 1 < NT) ? (t + 1) : (NT - 1);
        float4 xv[4];
        {
            const float* xp = x_all + ((size_t)(b0 + bb) * NT + tn) * NFIN;
#pragma unroll
            for (int i = 0; i < 4; ++i)
                xv[i] = *(const float4*)&xp[(q2 + 16 * i) * 4];
        }

        // ---- partials to LDS, transposed: pd[out][ks5] ----
#pragma unroll
        for (int jj = 0; jj < 8; ++jj)
#pragma unroll
            for (int i = 0; i < 4; ++i)
                pd[(jj * 16 + bq * 4 + i) * PD_STR + ks5] = ad[jj][i];
#pragma unroll
        for (int jq = 0; jq < 2; ++jq)
#pragma unroll
            for (int i = 0; i < 4; ++i)
                pd[(128 + jq * 16 + bq * 4 + i) * PD_STR + ks5] = az[jq][i];
        __syncthreads();

        // ---- reduce (float4 over ks5) + epilogue ----
        if (tid < 160) {
            const float* row = &pd[tid * PD_STR];
            float4 s4 = make_float4(0.f, 0.f, 0.f, 0.f);
#pragma unroll
            for (int q = 0; q < 16; ++q) {
                const float4 v = *(const float4*)&row[q * 4];
                s4.x += v.x; s4.y += v.y; s4.z += v.z; s4.w += v.w;
            }
            const float s = (s4.x + s4.y) + (s4.z + s4.w);
            if (tid < 128) {
                const float un = 0.9f * u_reg + 0.1f * (s + c_reg);
                u_reg = un;
                const float rv = tanhf(un) + xih_reg;
                const float* sp = rnxt + ep_addr;
                asm volatile("global_store_dword %0, %1, off sc0 sc1"
                             :: "v"(sp), "v"(rv) : "memory");
            } else {
                const float zv = s + zxi;
                const float* op = out + z_out_base + (size_t)t * NOUT;
                asm volatile("global_store_dword %0, %1, off sc0 sc1"
                             :: "v"(op), "v"(zv) : "memory");
            }
        }

        // drain write-through stores (to coherence point) + xv loads, per wave
        asm volatile("s_waitcnt vmcnt(0)" ::: "memory");
        __syncthreads();   // all blocks' r(t+1) slice is at L3 before arrive

        // ---- arrive: leaf -> root -> flag (tree cuts atomic serialization) ----
        if (tid == 0) {
            const unsigned lo = __hip_atomic_fetch_add(leaf, 1u, __ATOMIC_RELAXED,
                                                       __HIP_MEMORY_SCOPE_AGENT);
            if (lo == 8u * (unsigned)(t + 1) - 1u) {
                const unsigned ro = __hip_atomic_fetch_add(root, 1u, __ATOMIC_RELAXED,
                                                           __HIP_MEMORY_SCOPE_AGENT);
                if (ro == 16u * (unsigned)(t + 1) - 1u)
                    __hip_atomic_store(flg, (unsigned)(t + 1), __ATOMIC_RELAXED,
                                       __HIP_MEMORY_SCOPE_AGENT);
            }
        }

        // ---- write staged x (registers -> LDS), overlapping the wait window ----
        {
#pragma unroll
            for (int i = 0; i < 4; ++i) {
                const int kk = (q2 + 16 * i) * 4;
                const float4 v = xv[i];
                x_s[(kk + 0) * XS_STR + bb] = v.x;
                x_s[(kk + 1) * XS_STR + bb] = v.y;
                x_s[(kk + 2) * XS_STR + bb] = v.z;
                x_s[(kk + 3) * XS_STR + bb] = v.w;
            }
        }

        // ---- poll + acquire (inv) ----
        if (tid == 0) {
            while (__hip_atomic_load(flg, __ATOMIC_RELAXED,
                                     __HIP_MEMORY_SCOPE_AGENT) < (unsigned)(t + 1))
                __builtin_amdgcn_s_sleep(2);
            __builtin_amdgcn_fence(__ATOMIC_ACQUIRE, "agent");
        }
        __syncthreads();   // x_s(t+1) ready + inv done, block-wide

        float* tmp = (float*)rcur; rcur = rnxt; rnxt = tmp;
    }
}

// ---------------------------------------------------------------------------
extern "C" void kernel_launch(void* const* d_in, const int* in_sizes, int n_in,
                              void* d_out, int out_size, void* d_ws, size_t ws_size,
                              hipStream_t stream)
{
    const float* inputs = (const float*)d_in[0];  // [32,2000,256]
    const float* Wr     = (const float*)d_in[1];  // [1024,1024]
    const float* Wi     = (const float*)d_in[2];  // [256,1024]
    const float* Wf     = (const float*)d_in[3];  // [256,1024]
    const float* Wo     = (const float*)d_in[4];  // [1024,256]
    const float* xi_h   = (const float*)d_in[5];  // [32,1024]
    const float* xi_o   = (const float*)d_in[6];  // [32,256]
    float* out = (float*)d_out;

    float* ws     = (float*)d_ws;
    float* Wcb    = ws;                         // 128*1280*8
    float* Wot    = Wcb + 128 * KC * 8;         // 256*1024
    float* c_km   = Wot + NOUT * NH;
    float* xih_km = c_km + NH * NB;
    float* r0     = xih_km + NH * NB;
    float* r1     = r0 + NH * NB;
    unsigned* bar = (unsigned*)(r1 + NH * NB);  // 1024 uints (tree cells)

    (void)hipFuncSetAttribute((const void*)reservoir_persistent,
                              hipFuncAttributeMaxDynamicSharedMemorySize, LDS_BYTES);

    init_wcomb<<<KC, 256, 0, stream>>>(Wr, Wi, Wf, Wo, Wcb, Wot);
    init_state<<<NB, 256, 0, stream>>>(Wf, xi_o, xi_h, c_km, xih_km, r0, bar);

    void* args[] = {
        (void*)&inputs, (void*)&Wcb, (void*)&Wot, (void*)&c_km, (void*)&xih_km,
        (void*)&xi_o, (void*)&r0, (void*)&r1, (void*)&out, (void*)&bar
    };
    (void)hipLaunchCooperativeKernel((void*)reservoir_persistent,
                                     dim3(GRID), dim3(BLK), args, LDS_BYTES, stream);
}

// Round 4
// 14112.816 us; speedup vs baseline: 1.4219x; 1.2638x over previous
//
#include <hip/hip_runtime.h>
#include <math.h>

#define NB   32
#define NT   2000
#define NFIN 256
#define NH   1024
#define NOUT 256
#define KC   1280            // 1024 (r) + 256 (x)
#define GRID 256
#define BLK  256
#define HALF 128             // blocks per independent barrier group (one batch-half)

// ---- LDS partition (in floats) ----
#define WC_STR 12            // 8 cols + 4 pad
#define OFF_WC   0                          // 1280*12 = 15360
#define OFF_WOT  (OFF_WC + KC * WC_STR)     // 2*1024  =  2048
#define XS_STR   20                         // 16 batches + 4 pad
#define OFF_XS   (OFF_WOT + 2 * NH)         // 256*20  =  5120
#define PD_STR   68                         // 64 ks5 + 4 pad (transposed: [out][ks5])
#define OFF_PD   (OFF_XS + NFIN * XS_STR)   // 160*68  = 10880
#define LDS_FLOATS (OFF_PD + 160 * PD_STR)  // 33408 floats
#define LDS_BYTES  (LDS_FLOATS * 4)         // 133632 B (< 160 KiB)

// ---------------------------------------------------------------------------
// Wcomb block layout: Wcb[cg][k][8] = column 8*cg+jj at row k.
//   k <  1024 : 1.2*Wr[k][j] + sum_o Wo[k][o]*Wf[o][j]   (Weff = G*Wr + Wo@Wf)
//   k >= 1024 : Wi[k-1024][j]
// Also emits Wo^T: Wot[o][k] = Wo[k][o].
// ---------------------------------------------------------------------------
__global__ __launch_bounds__(256) void init_wcomb(
    const float* __restrict__ Wr, const float* __restrict__ Wi,
    const float* __restrict__ Wf, const float* __restrict__ Wo,
    float* __restrict__ Wcb, float* __restrict__ Wot)
{
    __shared__ float wo_s[NOUT];
    const int k   = blockIdx.x;      // 0..1279
    const int tid = threadIdx.x;
    float acc[4];
    if (k < NH) {
        wo_s[tid] = Wo[k * NOUT + tid];
        __syncthreads();
        Wot[(size_t)tid * NH + k] = wo_s[tid];   // transpose Wo
#pragma unroll
        for (int jj = 0; jj < 4; ++jj)
            acc[jj] = 1.2f * Wr[k * NH + jj * 256 + tid];
        for (int o = 0; o < NOUT; ++o) {
            const float w = wo_s[o];
#pragma unroll
            for (int jj = 0; jj < 4; ++jj)
                acc[jj] = fmaf(w, Wf[o * NH + jj * 256 + tid], acc[jj]);
        }
    } else {
        const int k2 = k - NH;
#pragma unroll
        for (int jj = 0; jj < 4; ++jj)
            acc[jj] = Wi[k2 * NH + jj * 256 + tid];
    }
#pragma unroll
    for (int jj = 0; jj < 4; ++jj) {
        const int j = jj * 256 + tid;
        Wcb[(size_t)(j >> 3) * (KC * 8) + k * 8 + (j & 7)] = acc[jj];
    }
}

// ---------------------------------------------------------------------------
// Per-batch init (k-major): c_km[j][b] = (xi_o @ Wf)[b][j],
// xih_km[j][b] = xi_h[b][j], r0[j][b] = xi_h (u0=0 -> tanh(0)=0).
// Also zeroes the barrier array (2048 unsigneds: tree cells, 64B-spaced).
// ---------------------------------------------------------------------------
__global__ __launch_bounds__(256) void init_state(
    const float* __restrict__ Wf, const float* __restrict__ xi_o,
    const float* __restrict__ xi_h,
    float* __restrict__ c_km, float* __restrict__ xih_km,
    float* __restrict__ r0, unsigned* __restrict__ bar)
{
    __shared__ float xo_s[NOUT];
    const int b   = blockIdx.x;
    const int tid = threadIdx.x;
    if (tid < 64) bar[b * 64 + tid] = 0u;   // 32 blocks x 64 = 2048 cells
    xo_s[tid] = xi_o[b * NOUT + tid];
    __syncthreads();
    float acc[4] = {0.f, 0.f, 0.f, 0.f};
    for (int o = 0; o < NOUT; ++o) {
        const float x = xo_s[o];
#pragma unroll
        for (int jj = 0; jj < 4; ++jj)
            acc[jj] = fmaf(x, Wf[o * NH + jj * 256 + tid], acc[jj]);
    }
#pragma unroll
    for (int jj = 0; jj < 4; ++jj) {
        const int j = jj * 256 + tid;
        const float xh = xi_h[b * NH + j];
        c_km[j * NB + b]   = acc[jj];
        xih_km[j * NB + b] = xh;
        r0[j * NB + b]     = xh;
    }
}

// ---------------------------------------------------------------------------
// Persistent kernel: 256 blocks x 256 threads. Block (bg=blk&1, cg=blk>>1):
// 16 batches x 8 du-cols + 2 z-cols. Thread (ks5=tid>>2, bq=tid&3): 64-way
// cyclic K split, tile 4 batches x (8 du + 2 z) accumulators.
//
// Sync scheme: producers write rnxt (and out) via sc0-sc1 write-through
// stores (coherence point) -> no release wbl2. Consumers keep cached r
// loads behind a per-step acquire buffer_inv.
// Arrival: 16 leaves (8 blocks) -> root (16). RELEASE: root completer
// writes SIXTEEN leaf-flag lines; each flag line is polled by only 8
// blocks -> no single-line poll-storm serializing the flag store and
// its fan-out (the R0-R3 release bottleneck).
// Per-half cell layout (1024 uints, 64B-spaced): leafcnt[lf] @ lf*16,
// root @ 256, leafflag[lf] @ 512 + lf*16.
// ---------------------------------------------------------------------------
extern "C" __global__ __launch_bounds__(BLK, 1) void reservoir_persistent(
    const float* __restrict__ x_all,  // [32][2000][256]
    const float* __restrict__ Wcb,    // [128][1280][8]
    const float* __restrict__ Wot,    // [256][1024]
    const float* __restrict__ c_km,   // [1024][32]
    const float* __restrict__ xih_km, // [1024][32]
    const float* __restrict__ xi_o,   // [32][256]
    float* __restrict__ r0, float* __restrict__ r1,   // [1024][32] each
    float* __restrict__ out,          // [32][2000][256]
    unsigned* __restrict__ bar)
{
    extern __shared__ float sm[];
    float* Wc_s  = sm + OFF_WC;
    float* Wot_s = sm + OFF_WOT;
    float* x_s   = sm + OFF_XS;
    float* pd    = sm + OFF_PD;      // [160][PD_STR]: rows 0..127 du, 128..159 z

    const int tid = threadIdx.x;
    const int blk = blockIdx.x;
    const int bg  = blk & 1;
    const int cg  = blk >> 1;
    const int b0  = bg * 16;
    const int j0  = cg * 8;
    const int zc0 = cg * 2;
    const int lf  = cg >> 3;         // leaf index 0..15 (8 blocks per leaf)

    unsigned* half_base = bar + (bg << 10);
    unsigned* leaf  = half_base + (lf << 4);
    unsigned* root  = half_base + 256;
    unsigned* lflag = half_base + 512 + (lf << 4);

    // ---- one-time: W tiles into LDS ----
#pragma unroll
    for (int i = 0; i < 10; ++i) {
        const int q = tid + BLK * i;          // 2560 float4 quads
        const int k = q >> 1, h = q & 1;
        const float4 w = *(const float4*)&Wcb[(size_t)cg * (KC * 8) + k * 8 + h * 4];
        *(float4*)&Wc_s[k * WC_STR + h * 4] = w;
    }
#pragma unroll
    for (int i = 0; i < 8; ++i) {
        const int idx = tid + BLK * i;        // 2048 floats
        Wot_s[idx] = Wot[(size_t)zc0 * NH + idx];
    }

    // ---- epilogue state in registers ----
    float u_reg = 0.f, c_reg = 0.f, xih_reg = 0.f;
    int ep_addr = 0;
    if (tid < 128) {
        const int j = j0 + (tid >> 4);
        const int b = b0 + (tid & 15);
        ep_addr = j * NB + b;
        c_reg   = c_km[ep_addr];
        xih_reg = xih_km[ep_addr];
    }
    float zxi = 0.f; size_t z_out_base = 0;
    if (tid >= 128 && tid < 160) {
        const int o2 = tid - 128;
        const int zc = zc0 + (o2 >> 4);
        const int zb = b0 + (o2 & 15);
        zxi = xi_o[zb * NOUT + zc];
        z_out_base = (size_t)zb * NT * NOUT + zc;
    }

    const int ks5 = tid >> 2;   // 0..63
    const int bq  = tid & 3;    // 0..3
    // x-stage mapping (swizzled for conflict-free LDS stores)
    const int bb  = tid & 15;   // batch row
    const int q2  = tid >> 4;   // quad group 0..15

    const float* rcur = r0;
    float*       rnxt = r1;

    // ---- stage x for t=0 ----
    {
        const float* xp = x_all + ((size_t)(b0 + bb) * NT + 0) * NFIN;
#pragma unroll
        for (int i = 0; i < 4; ++i) {
            const int kk = (q2 + 16 * i) * 4;
            const float4 v = *(const float4*)&xp[kk];
            x_s[(kk + 0) * XS_STR + bb] = v.x;
            x_s[(kk + 1) * XS_STR + bb] = v.y;
            x_s[(kk + 2) * XS_STR + bb] = v.z;
            x_s[(kk + 3) * XS_STR + bb] = v.w;
        }
    }
    __syncthreads();

    for (int t = 0; t < NT; ++t) {
        // ---- main GEMM walk (r part, FULL-depth prefetch: all 16 float4) ----
        float ad[8][4], az[2][4];
#pragma unroll
        for (int jj = 0; jj < 8; ++jj)
#pragma unroll
            for (int i = 0; i < 4; ++i) ad[jj][i] = 0.f;
#pragma unroll
        for (int jq = 0; jq < 2; ++jq)
#pragma unroll
            for (int i = 0; i < 4; ++i) az[jq][i] = 0.f;

        const float* rbase = rcur + b0 + bq * 4;
        float4 rq4[16];
#pragma unroll
        for (int p = 0; p < 16; ++p)
            rq4[p] = *(const float4*)(rbase + (size_t)(ks5 + (p << 6)) * NB);

#pragma unroll
        for (int m = 0; m < 16; ++m) {
            const int k = ks5 + (m << 6);
            const float4 a = rq4[m];
            const float4 w0 = *(const float4*)&Wc_s[k * WC_STR];
            const float4 w1 = *(const float4*)&Wc_s[k * WC_STR + 4];
            const float z0 = Wot_s[k], z1 = Wot_s[NH + k];
            const float av[4] = {a.x, a.y, a.z, a.w};
            const float wv[8] = {w0.x, w0.y, w0.z, w0.w, w1.x, w1.y, w1.z, w1.w};
#pragma unroll
            for (int i = 0; i < 4; ++i) {
#pragma unroll
                for (int jj = 0; jj < 8; ++jj)
                    ad[jj][i] = fmaf(av[i], wv[jj], ad[jj][i]);
                az[0][i] = fmaf(av[i], z0, az[0][i]);
                az[1][i] = fmaf(av[i], z1, az[1][i]);
            }
        }
#pragma unroll
        for (int m = 0; m < 4; ++m) {         // x part: k >= 1024
            const int kk = ks5 + (m << 6);
            const int k  = kk + NH;
            const float4 a  = *(const float4*)&x_s[kk * XS_STR + bq * 4];
            const float4 w0 = *(const float4*)&Wc_s[k * WC_STR];
            const float4 w1 = *(const float4*)&Wc_s[k * WC_STR + 4];
            const float av[4] = {a.x, a.y, a.z, a.w};
            const float wv[8] = {w0.x, w0.y, w0.z, w0.w, w1.x, w1.y, w1.z, w1.w};
#pragma unroll
            for (int i = 0; i < 4; ++i)
#pragma unroll
                for (int jj = 0; jj < 8; ++jj)
                    ad[jj][i] = fmaf(av[i], wv[jj], ad[jj][i]);
        }

        // ---- issue t+1 x loads into registers NOW (fly under pd+sync+reduce) ----
        const int tn = (t + 1 < NT) ? (t + 1) : (NT - 1);
        float4 xv[4];
        {
            const float* xp = x_all + ((size_t)(b0 + bb) * NT + tn) * NFIN;
#pragma unroll
            for (int i = 0; i < 4; ++i)
                xv[i] = *(const float4*)&xp[(q2 + 16 * i) * 4];
        }

        // ---- partials to LDS, transposed: pd[out][ks5] ----
#pragma unroll
        for (int jj = 0; jj < 8; ++jj)
#pragma unroll
            for (int i = 0; i < 4; ++i)
                pd[(jj * 16 + bq * 4 + i) * PD_STR + ks5] = ad[jj][i];
#pragma unroll
        for (int jq = 0; jq < 2; ++jq)
#pragma unroll
            for (int i = 0; i < 4; ++i)
                pd[(128 + jq * 16 + bq * 4 + i) * PD_STR + ks5] = az[jq][i];
        __syncthreads();

        // ---- reduce (float4 over ks5) + epilogue ----
        if (tid < 160) {
            const float* row = &pd[tid * PD_STR];
            float4 s4 = make_float4(0.f, 0.f, 0.f, 0.f);
#pragma unroll
            for (int q = 0; q < 16; ++q) {
                const float4 v = *(const float4*)&row[q * 4];
                s4.x += v.x; s4.y += v.y; s4.z += v.z; s4.w += v.w;
            }
            const float s = (s4.x + s4.y) + (s4.z + s4.w);
            if (tid < 128) {
                const float un = 0.9f * u_reg + 0.1f * (s + c_reg);
                u_reg = un;
                const float rv = tanhf(un) + xih_reg;
                const float* sp = rnxt + ep_addr;
                asm volatile("global_store_dword %0, %1, off sc0 sc1"
                             :: "v"(sp), "v"(rv) : "memory");
            } else {
                const float zv = s + zxi;
                const float* op = out + z_out_base + (size_t)t * NOUT;
                asm volatile("global_store_dword %0, %1, off sc0 sc1"
                             :: "v"(op), "v"(zv) : "memory");
            }
        }

        // drain per wave before arrive. Waves 0/1: r-stores must reach the
        // coherence point -> vmcnt(0). Wave 2: its newest VM op is the out
        // store (never read on-device) -> vmcnt(1) retires the 4 older xv
        // loads (vmcnt retires in issue order) and lets the out store fly
        // across the barrier. Wave 3: only xv loads -> vmcnt(0).
        if ((tid >> 6) == 2) {
            asm volatile("s_waitcnt vmcnt(1)" ::: "memory");
        } else {
            asm volatile("s_waitcnt vmcnt(0)" ::: "memory");
        }
        __syncthreads();   // all blocks' r(t+1) slice is at L3 before arrive

        // ---- arrive: leaf -> root; completer fans the release out over
        //      16 separate flag lines (8 pollers each) ----
        if (tid == 0) {
            const unsigned lo = __hip_atomic_fetch_add(leaf, 1u, __ATOMIC_RELAXED,
                                                       __HIP_MEMORY_SCOPE_AGENT);
            if (lo == 8u * (unsigned)(t + 1) - 1u) {
                const unsigned ro = __hip_atomic_fetch_add(root, 1u, __ATOMIC_RELAXED,
                                                           __HIP_MEMORY_SCOPE_AGENT);
                if (ro == 16u * (unsigned)(t + 1) - 1u) {
#pragma unroll
                    for (int f = 0; f < 16; ++f)
                        __hip_atomic_store(half_base + 512 + (f << 4),
                                           (unsigned)(t + 1), __ATOMIC_RELAXED,
                                           __HIP_MEMORY_SCOPE_AGENT);
                }
            }
        }

        // ---- write staged x (registers -> LDS), overlapping the wait window ----
        {
#pragma unroll
            for (int i = 0; i < 4; ++i) {
                const int kk = (q2 + 16 * i) * 4;
                const float4 v = xv[i];
                x_s[(kk + 0) * XS_STR + bb] = v.x;
                x_s[(kk + 1) * XS_STR + bb] = v.y;
                x_s[(kk + 2) * XS_STR + bb] = v.z;
                x_s[(kk + 3) * XS_STR + bb] = v.w;
            }
        }

        // ---- poll own leaf flag + acquire (inv) ----
        if (tid == 0) {
            while (__hip_atomic_load(lflag, __ATOMIC_RELAXED,
                                     __HIP_MEMORY_SCOPE_AGENT) < (unsigned)(t + 1))
                __builtin_amdgcn_s_sleep(1);
            __builtin_amdgcn_fence(__ATOMIC_ACQUIRE, "agent");
        }
        __syncthreads();   // x_s(t+1) ready + inv done, block-wide

        float* tmp = (float*)rcur; rcur = rnxt; rnxt = tmp;
    }
}

// ---------------------------------------------------------------------------
extern "C" void kernel_launch(void* const* d_in, const int* in_sizes, int n_in,
                              void* d_out, int out_size, void* d_ws, size_t ws_size,
                              hipStream_t stream)
{
    const float* inputs = (const float*)d_in[0];  // [32,2000,256]
    const float* Wr     = (const float*)d_in[1];  // [1024,1024]
    const float* Wi     = (const float*)d_in[2];  // [256,1024]
    const float* Wf     = (const float*)d_in[3];  // [256,1024]
    const float* Wo     = (const float*)d_in[4];  // [1024,256]
    const float* xi_h   = (const float*)d_in[5];  // [32,1024]
    const float* xi_o   = (const float*)d_in[6];  // [32,256]
    float* out = (float*)d_out;

    float* ws     = (float*)d_ws;
    float* Wcb    = ws;                         // 128*1280*8
    float* Wot    = Wcb + 128 * KC * 8;         // 256*1024
    float* c_km   = Wot + NOUT * NH;
    float* xih_km = c_km + NH * NB;
    float* r0     = xih_km + NH * NB;
    float* r1     = r0 + NH * NB;
    unsigned* bar = (unsigned*)(r1 + NH * NB);  // 2048 uints (tree + flag lines)

    (void)hipFuncSetAttribute((const void*)reservoir_persistent,
                              hipFuncAttributeMaxDynamicSharedMemorySize, LDS_BYTES);

    init_wcomb<<<KC, 256, 0, stream>>>(Wr, Wi, Wf, Wo, Wcb, Wot);
    init_state<<<NB, 256, 0, stream>>>(Wf, xi_o, xi_h, c_km, xih_km, r0, bar);

    void* args[] = {
        (void*)&inputs, (void*)&Wcb, (void*)&Wot, (void*)&c_km, (void*)&xih_km,
        (void*)&xi_o, (void*)&r0, (void*)&r1, (void*)&out, (void*)&bar
    };
    (void)hipLaunchCooperativeKernel((void*)reservoir_persistent,
                                     dim3(GRID), dim3(BLK), args, LDS_BYTES, stream);
}